// Round 6
// baseline (3168.965 us; speedup 1.0000x reference)
//
#include <hip/hip_runtime.h>

typedef unsigned short ushort_t;
typedef unsigned int uint_t;
typedef __attribute__((ext_vector_type(8))) short bf16x8;
typedef __attribute__((ext_vector_type(4))) float f32x4;
typedef __attribute__((ext_vector_type(4))) unsigned int uintx4;

#define B_  16
#define S_  1024
#define D_  1024
#define U_  512
#define GU_ 1536  // 3*U

// ---------- bf16 helpers (RNE) ----------
__device__ __forceinline__ ushort_t f2bf(float f) {
  union { float f; uint_t u; } v; v.f = f;
  uint_t r = v.u + 0x7fffu + ((v.u >> 16) & 1u);
  return (ushort_t)(r >> 16);
}
__device__ __forceinline__ float bf2f(ushort_t b) {
  union { uint_t u; float f; } v; v.u = ((uint_t)b) << 16; return v.f;
}

// ---------- fp32 -> bf16 weight conversion ----------
__global__ void cvt_f32_bf16(const float4* __restrict__ in, ushort4* __restrict__ out, int n4) {
  int i = blockIdx.x * blockDim.x + threadIdx.x;
  int stride = gridDim.x * blockDim.x;
  for (; i < n4; i += stride) {
    float4 f = in[i];
    ushort4 o; o.x = f2bf(f.x); o.y = f2bf(f.y); o.z = f2bf(f.z); o.w = f2bf(f.w);
    out[i] = o;
  }
}

// ---------- LayerNorm: x fp32 [BS, 1024] -> xn bf16 ----------
__global__ __launch_bounds__(256) void ln_kernel(
    const float* __restrict__ x, const float* __restrict__ gamma,
    const float* __restrict__ beta, ushort_t* __restrict__ xn)
{
  int row = blockIdx.x;
  int t = threadIdx.x;
  const float* xr = x + (size_t)row * 1024;
  float4 v = *(const float4*)(xr + t * 4);
  float s = v.x + v.y + v.z + v.w;
  float ss = v.x * v.x + v.y * v.y + v.z * v.z + v.w * v.w;
#pragma unroll
  for (int o = 32; o > 0; o >>= 1) {
    s  += __shfl_down(s, o, 64);
    ss += __shfl_down(ss, o, 64);
  }
  __shared__ float red[2][4];
  __shared__ float mv[2];
  int wv = t >> 6, ln = t & 63;
  if (ln == 0) { red[0][wv] = s; red[1][wv] = ss; }
  __syncthreads();
  if (t == 0) {
    float S1 = red[0][0] + red[0][1] + red[0][2] + red[0][3];
    float S2 = red[1][0] + red[1][1] + red[1][2] + red[1][3];
    float mu = S1 * (1.f / 1024.f);
    float var = S2 * (1.f / 1024.f) - mu * mu;
    mv[0] = mu;
    mv[1] = rsqrtf(var + 1e-5f);
  }
  __syncthreads();
  float mu = mv[0], rs = mv[1];
  float4 gm = *(const float4*)(gamma + t * 4);
  float4 bt = *(const float4*)(beta + t * 4);
  ushort4 o;
  o.x = f2bf((v.x - mu) * rs * gm.x + bt.x);
  o.y = f2bf((v.y - mu) * rs * gm.y + bt.y);
  o.z = f2bf((v.z - mu) * rs * gm.z + bt.z);
  o.w = f2bf((v.w - mu) * rs * gm.w + bt.w);
  *(ushort4*)(xn + (size_t)row * 1024 + t * 4) = o;
}

// ---------- GEMM: C[M,N] = A[M,K](bf16) @ Bw[N,K](bf16)^T + bias (+resid) ----------
template<int RES, int OBF>
__global__ __launch_bounds__(256, 2) void gemm_bt(
    const ushort_t* __restrict__ A, const ushort_t* __restrict__ Bw,
    const float* __restrict__ bias, const float* __restrict__ resid,
    void* __restrict__ Cout, int M, int N, int K)
{
  __shared__ ushort_t As[128][40];
  __shared__ ushort_t Bs[128][40];
  int bm = blockIdx.x, bn = blockIdx.y;
  int tid = threadIdx.x;
  int wave = tid >> 6, lane = tid & 63;
  int wm = wave >> 1, wn = wave & 1;
  int q = lane >> 4, l16 = lane & 15;
  f32x4 acc[4][4];
#pragma unroll
  for (int i = 0; i < 4; i++)
#pragma unroll
    for (int j = 0; j < 4; j++) acc[i][j] = (f32x4){0.f, 0.f, 0.f, 0.f};
  int r0 = tid >> 2, kc = tid & 3;
  const int nk = K >> 5;
  for (int it = 0; it < nk; ++it) {
#pragma unroll
    for (int h = 0; h < 2; ++h) {
      int r = r0 + h * 64;
      const uint4* pa = (const uint4*)(A + (size_t)(bm * 128 + r) * K + it * 32 + kc * 8);
      *(uint4*)&As[r][kc * 8] = *pa;
      const uint4* pb = (const uint4*)(Bw + (size_t)(bn * 128 + r) * K + it * 32 + kc * 8);
      *(uint4*)&Bs[r][kc * 8] = *pb;
    }
    __syncthreads();
    bf16x8 af[4], bfr[4];
#pragma unroll
    for (int i = 0; i < 4; i++) af[i]  = *(bf16x8*)&As[wm * 64 + i * 16 + l16][q * 8];
#pragma unroll
    for (int j = 0; j < 4; j++) bfr[j] = *(bf16x8*)&Bs[wn * 64 + j * 16 + l16][q * 8];
#pragma unroll
    for (int i = 0; i < 4; i++)
#pragma unroll
      for (int j = 0; j < 4; j++)
        acc[i][j] = __builtin_amdgcn_mfma_f32_16x16x32_bf16(af[i], bfr[j], acc[i][j], 0, 0, 0);
    __syncthreads();
  }
#pragma unroll
  for (int i = 0; i < 4; i++) {
#pragma unroll
    for (int j = 0; j < 4; j++) {
      int n = bn * 128 + wn * 64 + j * 16 + l16;
      float bv = bias[n];
#pragma unroll
      for (int rr = 0; rr < 4; rr++) {
        int m = bm * 128 + wm * 64 + i * 16 + q * 4 + rr;
        float v = acc[i][j][rr] + bv;
        if (RES) v += resid[(size_t)m * N + n];
        if (OBF) ((ushort_t*)Cout)[(size_t)m * N + n] = f2bf(v);
        else     ((float*)Cout)[(size_t)m * N + n] = v;
      }
    }
  }
}

// ---------- GRU scan (16 wgs, SELF-TAGGED mailbox, 2 L3 hops/step) ----------
// wg m owns h-cols [32m,32m+32) for all 16 batches. Mailbox dword per
// (step-parity, b, col): bf16(h)<<16 | (step+1). Writer: fire-and-forget
// sc0-sc1 stores — NO drain, NO separate tag (tag rides in every dword).
// Reader: burst-read the 32 KB slot, validate tags in-register, per-wave
// retry. 2-slot ping-pong safe: wg X publishes step s only after BOTH its
// waves validated all of slot s-1 (barrier before compute), which certifies
// every wg published s-1, which (program order) certifies every wg consumed
// slot s-2 — the parity being overwritten.
// Barriers: raw s_barrier between publish and poll (no vmcnt drain needed:
// the compiler's lgkmcnt-before-MFMA guarantees the sibling wave consumed
// its LDS reads before arriving); full __syncthreads only after staging.
__global__ __launch_bounds__(128, 1) void scan_kernel(
    const ushort_t* __restrict__ gx, const float* __restrict__ w_hh,
    const float* __restrict__ b_hh, uint_t* __restrict__ mdata,
    ushort_t* __restrict__ y, float* __restrict__ h_last)
{
  extern __shared__ char smem[];
  ushort_t* wlds = (ushort_t*)smem;   // 48 KB: [gi*16+wv*8+ks][lane][8] B-frags, ks 0..7
  char* hshb = smem + 49152;          // 16 KB: [b][512] bf16, 16B-chunk XOR-(b&7) swizzle

  const int m = blockIdx.x;
  const int c0 = m * 32;
  const int t = threadIdx.x;
  const int wv = t >> 6, lane = t & 63, q = lane >> 4, l16 = lane & 15;
  const int cl = (wv << 4) + l16;      // owned hcol within slice, 0..31

  // ---- w_hh ks=0..7 fragments into LDS (both waves' col-halves) ----
  for (int idx = t; idx < 48 * 64; idx += 128) {
    int cc = idx >> 6, ln = idx & 63;
    int gi = cc >> 4, wv2 = (cc >> 3) & 1, ks = cc & 7;
    int n = c0 + (wv2 << 4) + (ln & 15);
    int k0 = (ks << 5) + ((ln >> 4) << 3);
    const float* src = w_hh + (size_t)(gi * 512 + n) * 512 + k0;
    float4 f0 = *(const float4*)src;
    float4 f1 = *(const float4*)(src + 4);
    uint4 pk;
    pk.x = (uint_t)f2bf(f0.x) | ((uint_t)f2bf(f0.y) << 16);
    pk.y = (uint_t)f2bf(f0.z) | ((uint_t)f2bf(f0.w) << 16);
    pk.z = (uint_t)f2bf(f1.x) | ((uint_t)f2bf(f1.y) << 16);
    pk.w = (uint_t)f2bf(f1.z) | ((uint_t)f2bf(f1.w) << 16);
    *(uint4*)(wlds + (size_t)cc * 512 + ln * 8) = pk;
  }
  // ---- w_hh ks=8..15 fragments in VGPRs (96 regs) ----
  bf16x8 wreg[3][8];
#pragma unroll
  for (int gi = 0; gi < 3; ++gi)
#pragma unroll
    for (int k8 = 0; k8 < 8; ++k8) {
      const float* src = w_hh + (size_t)(gi * 512 + c0 + cl) * 512 + (8 + k8) * 32 + q * 8;
      float4 f0 = *(const float4*)src;
      float4 f1 = *(const float4*)(src + 4);
      bf16x8 wf;
      wf[0] = (short)f2bf(f0.x); wf[1] = (short)f2bf(f0.y);
      wf[2] = (short)f2bf(f0.z); wf[3] = (short)f2bf(f0.w);
      wf[4] = (short)f2bf(f1.x); wf[5] = (short)f2bf(f1.y);
      wf[6] = (short)f2bf(f1.z); wf[7] = (short)f2bf(f1.w);
      wreg[gi][k8] = wf;
    }

  const float bhr = b_hh[c0 + cl];
  const float bhz = b_hh[512 + c0 + cl];
  const float bhn = b_hh[1024 + c0 + cl];
  float hcur[4] = {0.f, 0.f, 0.f, 0.f};

  // gx for step 0
  ushort_t gxv[3][4];
#pragma unroll
  for (int g = 0; g < 3; ++g)
#pragma unroll
    for (int r = 0; r < 4; ++r)
      gxv[g][r] = gx[(size_t)(((q << 2) + r) * S_) * GU_ + g * 512 + c0 + cl];

  // h_0 = 0
  for (int i = t; i < 4096; i += 128) ((uint_t*)hshb)[i] = 0u;

  for (int step = 0; step < S_; ++step) {
    if (step > 0) {
      const uint_t want = (uint_t)step;   // h_step published at end of step-1
      const uint_t* db = mdata + (((step - 1) & 1) << 13);
      uintx4 vals[16];
      // ---- burst-read the whole 32 KB slot; per-wave retry on stale tags ----
      for (;;) {
#pragma unroll
        for (int j = 0; j < 16; ++j) {
          const uint_t* p = db + j * 512 + t * 4;
          asm volatile("global_load_dwordx4 %0, %1, off sc0 sc1"
                       : "=v"(vals[j]) : "v"(p) : "memory");
        }
        asm volatile("s_waitcnt vmcnt(0)" ::: "memory");
        uint_t bad = 0u;
#pragma unroll
        for (int j = 0; j < 16; ++j) {
          uintx4 v = vals[j];
          bad |= ((v.x ^ want) | (v.y ^ want) | (v.z ^ want) | (v.w ^ want)) & 0xffffu;
        }
        if (!__any((int)bad)) break;
      }
      // ---- stage: vals[j] = batch j, cols 4t..4t+3 (tag in lo16, data hi16) ----
#pragma unroll
      for (int j = 0; j < 16; ++j) {
        uintx4 v = vals[j];
        uint2 dw;
        dw.x = (v.x >> 16) | (v.y & 0xffff0000u);
        dw.y = (v.z >> 16) | (v.w & 0xffff0000u);
        *(uint2*)(hshb + j * 1024 + (((t >> 1) ^ (j & 7)) << 4) + ((t & 1) << 3)) = dw;
      }
    }
    __syncthreads();   // staging visible to both waves (lgkm drain)

    // ---- MFMA: gh tiles (rows=batch, cols=this wave's 16 hcols x 3 gates) ----
    f32x4 acc[3] = {{0.f,0.f,0.f,0.f},{0.f,0.f,0.f,0.f},{0.f,0.f,0.f,0.f}};
#pragma unroll
    for (int ks = 0; ks < 16; ++ks) {
      bf16x8 hf = *(bf16x8*)(hshb + l16 * 1024 +
                             ((((ks << 2) + q) ^ (l16 & 7)) << 4));
#pragma unroll
      for (int gi = 0; gi < 3; ++gi) {
        bf16x8 wf;
        if (ks < 8) wf = *(bf16x8*)(wlds + (size_t)((gi * 2 + wv) * 8 + ks) * 512 + lane * 8);
        else        wf = wreg[gi][ks - 8];
        acc[gi] = __builtin_amdgcn_mfma_f32_16x16x32_bf16(hf, wf, acc[gi], 0, 0, 0);
      }
    }

    // ---- gates (row=batch=q*4+r, col=c0+cl) ----
    ushort_t hb16[4];
#pragma unroll
    for (int r = 0; r < 4; ++r) {
      float xr  = bf2f(gxv[0][r]);
      float xz  = bf2f(gxv[1][r]);
      float xnn = bf2f(gxv[2][r]);
      float rr = 1.f / (1.f + __expf(-(xr + acc[0][r] + bhr)));
      float zz = 1.f / (1.f + __expf(-(xz + acc[1][r] + bhz)));
      float na = xnn + rr * (acc[2][r] + bhn);
      float ng = 1.f - 2.f / (1.f + __expf(2.f * na));   // tanh, inf-safe
      float hv = (1.f - zz) * ng + zz * hcur[r];
      hcur[r] = hv;
      hb16[r] = f2bf(hv);
    }

    // ---- self-tagged publish: fire-and-forget, all 64 lanes ----
    if (step < S_ - 1) {
      const uint_t tagout = (uint_t)(step + 1);
      uint_t* pb = mdata + ((step & 1) << 13);
#pragma unroll
      for (int r = 0; r < 4; ++r) {
        uint_t dw = (((uint_t)hb16[r]) << 16) | tagout;
        uint_t* pp = pb + ((q << 2) + r) * 512 + c0 + cl;
        asm volatile("global_store_dword %0, %1, off sc0 sc1"
                     :: "v"(pp), "v"(dw) : "memory");
      }
    }

    // ---- y stores (plain cached; drained by next poll's vmcnt(0)) ----
#pragma unroll
    for (int r = 0; r < 4; ++r)
      y[((size_t)((q << 2) + r) * S_ + step) * U_ + c0 + cl] = hb16[r];

    // ---- gx prefetch for next step (in flight across the next poll) ----
    if (step + 1 < S_) {
#pragma unroll
      for (int g = 0; g < 3; ++g)
#pragma unroll
        for (int r = 0; r < 4; ++r)
          gxv[g][r] = gx[((size_t)((q << 2) + r) * S_ + step + 1) * GU_ +
                         g * 512 + c0 + cl];
    }

    // raw barrier (no vmcnt drain): sibling wave finished its LDS reads
    // (compiler waits lgkmcnt before MFMA use) => next staging can't corrupt.
    asm volatile("s_barrier" ::: "memory");
  }

#pragma unroll
  for (int r = 0; r < 4; ++r)
    h_last[((q << 2) + r) * 512 + c0 + cl] = hcur[r];
}

extern "C" void kernel_launch(void* const* d_in, const int* in_sizes, int n_in,
                              void* d_out, int out_size, void* d_ws, size_t ws_size,
                              hipStream_t stream) {
  const float* x     = (const float*)d_in[0];
  const float* ln_g  = (const float*)d_in[1];
  const float* ln_b  = (const float*)d_in[2];
  const float* w_in  = (const float*)d_in[3];
  const float* b_in  = (const float*)d_in[4];
  const float* w_ih  = (const float*)d_in[5];
  const float* w_hh  = (const float*)d_in[6];
  const float* b_ih  = (const float*)d_in[7];
  const float* b_hh  = (const float*)d_in[8];
  const float* w_out = (const float*)d_in[9];
  const float* b_out = (const float*)d_in[10];

  float* out = (float*)d_out;                       // [B,S,D] fp32
  float* h_last = out + (size_t)B_ * S_ * D_;       // [B,U] fp32

  char* ws = (char*)d_ws;
  size_t off = 0;
  ushort_t* xn   = (ushort_t*)(ws + off); off += (size_t)B_ * S_ * D_ * 2;   // 32 MB
  ushort_t* u    = (ushort_t*)(ws + off); off += (size_t)B_ * S_ * U_ * 2;   // 16 MB
  ushort_t* gx   = (ushort_t*)(ws + off); off += (size_t)B_ * S_ * GU_ * 2;  // 48 MB
  ushort_t* y    = (ushort_t*)(ws + off); off += (size_t)B_ * S_ * U_ * 2;   // 16 MB
  ushort_t* winb = (ushort_t*)(ws + off); off += (size_t)U_ * D_ * 2;
  ushort_t* wihb = (ushort_t*)(ws + off); off += (size_t)GU_ * U_ * 2;
  ushort_t* woub = (ushort_t*)(ws + off); off += (size_t)D_ * U_ * 2;
  // self-tagged data mailbox (2 slots x 32 KB) aliases the dead xn buffer:
  // xn's last use is GEMM1 (stream-ordered before the scan). Stale LN bf16
  // bits / 0xAA poison in the tag halfword can't forge tags 1..1024 (would
  // require |x| < 2^-118).
  uint_t* mdata  = (uint_t*)xn;

  cvt_f32_bf16<<<512, 256, 0, stream>>>((const float4*)w_in,  (ushort4*)winb, U_ * D_ / 4);
  cvt_f32_bf16<<<512, 256, 0, stream>>>((const float4*)w_ih,  (ushort4*)wihb, GU_ * U_ / 4);
  cvt_f32_bf16<<<512, 256, 0, stream>>>((const float4*)w_out, (ushort4*)woub, D_ * U_ / 4);

  ln_kernel<<<B_ * S_, 256, 0, stream>>>(x, ln_g, ln_b, xn);

  // u = xn @ w_in^T + b_in  (M=16384, N=512, K=1024)
  gemm_bt<0, 1><<<dim3(B_ * S_ / 128, U_ / 128), 256, 0, stream>>>(
      xn, winb, b_in, nullptr, u, B_ * S_, U_, D_);
  // gx = u @ w_ih^T + b_ih  (M=16384, N=1536, K=512)
  gemm_bt<0, 1><<<dim3(B_ * S_ / 128, GU_ / 128), 256, 0, stream>>>(
      u, wihb, b_ih, nullptr, gx, B_ * S_, GU_, U_);

  // sequential GRU: 16 wgs x 128 threads, 64 KB pure-dynamic LDS
  (void)hipFuncSetAttribute(reinterpret_cast<const void*>(scan_kernel),
                            hipFuncAttributeMaxDynamicSharedMemorySize, 65536);
  scan_kernel<<<16, 128, 65536, stream>>>(gx, w_hh, b_hh, mdata, y, h_last);

  // out = x + y @ w_out^T + b_out  (M=16384, N=1024, K=512)
  gemm_bt<1, 0><<<dim3(B_ * S_ / 128, D_ / 128), 256, 0, stream>>>(
      y, woub, b_out, x, out, B_ * S_, D_, U_);
}